// Round 6
// baseline (730.019 us; speedup 1.0000x reference)
//
#include <hip/hip_runtime.h>
#include <stdint.h>

// Problem constants
#define BB 16384
#define II 512
#define HH 1024
#define OO 512

typedef short s16x8 __attribute__((ext_vector_type(8)));
typedef float f32x4 __attribute__((ext_vector_type(4)));

__device__ __forceinline__ unsigned short f2bf(float x) {
  union { float f; unsigned u; } v; v.f = x;
  return (unsigned short)((v.u + 0x7fffu + ((v.u >> 16) & 1u)) >> 16);  // RNE
}
__device__ __forceinline__ float bf2f(unsigned short b) {
  union { unsigned u; float f; } v; v.u = ((unsigned)b) << 16;
  return v.f;
}
__device__ __forceinline__ float sigmoid_f(float x) {
  return 1.0f / (1.0f + __expf(-x));
}
__device__ __forceinline__ float tanh_f(float x) {
  float ax = fabsf(x);
  float e = __expf(-2.0f * ax);
  float t = (1.0f - e) / (1.0f + e);
  return x >= 0.0f ? t : -t;
}

// async global->LDS, 16B per lane, LDS dest = wave-uniform base + lane*16
__device__ __forceinline__ void stage16(const void* g, void* l) {
  __builtin_amdgcn_global_load_lds((const __attribute__((address_space(1))) void*)g,
                                   (__attribute__((address_space(3))) void*)l,
                                   16, 0, 0);
}

// ---- 128-tile helper (kept for gemm_out) ----
__device__ __forceinline__ void mma_step64(const unsigned short* As, const unsigned short* Bs,
                                           f32x4 acc[4][4], int lane, int wave) {
  const int wm = wave & 1, wn = wave >> 1;
  const int ln = lane & 15, q = lane >> 4;
#pragma unroll
  for (int s = 0; s < 2; ++s) {
    s16x8 af[4], bfr[4];
#pragma unroll
    for (int i = 0; i < 4; ++i) {
      const int r = wm * 64 + i * 16 + ln;
      af[i] = *(const s16x8*)(As + r * 64 + ((((s << 2) + q) + r) & 7) * 8);
    }
#pragma unroll
    for (int i = 0; i < 4; ++i) {
      const int r = wn * 64 + i * 16 + ln;
      bfr[i] = *(const s16x8*)(Bs + r * 64 + ((((s << 2) + q) + r) & 7) * 8);
    }
#pragma unroll
    for (int mi = 0; mi < 4; ++mi)
#pragma unroll
      for (int ni = 0; ni < 4; ++ni)
        acc[mi][ni] = __builtin_amdgcn_mfma_f32_16x16x32_bf16(af[mi], bfr[ni], acc[mi][ni], 0, 0, 0);
  }
}

// ---------------- fused prep kernel ----------------
__global__ __launch_bounds__(256) void prep_all(const float* __restrict__ inp,
                                                const float* __restrict__ h,
                                                const float* __restrict__ Wx,
                                                const float* __restrict__ Wh,
                                                const float* __restrict__ Wout,
                                                unsigned short* __restrict__ Xb,
                                                unsigned short* __restrict__ Hlo,
                                                unsigned short* __restrict__ Wg,
                                                unsigned short* __restrict__ Wz2,
                                                unsigned short* __restrict__ Wo) {
  const int bid = blockIdx.x;
  if (bid < 12288) {
    int t = bid * 256 + threadIdx.x;
    int base = t * 8;
    int b = base / 1536;
    int k = base - b * 1536;
    const float* src = (k < 512) ? (inp + b * 512 + k) : (h + b * 1024 + (k - 512));
    float4 v0 = *(const float4*)src;
    float4 v1 = *(const float4*)(src + 4);
    float f[8] = {v0.x, v0.y, v0.z, v0.w, v1.x, v1.y, v1.z, v1.w};
    unsigned short hi[8];
#pragma unroll
    for (int i = 0; i < 8; ++i) hi[i] = f2bf(f[i]);
    *(s16x8*)(Xb + base) = *(s16x8*)hi;
    if (k >= 512) {
      unsigned short lo[8];
#pragma unroll
      for (int i = 0; i < 8; ++i) lo[i] = f2bf(f[i] - bf2f(hi[i]));
      *(s16x8*)(Hlo + b * 1024 + (k - 512)) = *(s16x8*)lo;
    }
  } else if (bid < 15360) {
    // Wg: [4096][1536], columns permuted: n = blkX*256 + wn*64 + gate*16 + ln
    int t = (bid - 12288) * 256 + threadIdx.x;
    int base = t * 8;
    int n = base / 1536;
    int k = base - n * 1536;
    int r = n & 255;
    int gate = (r >> 4) & 3;
    int unit = ((n >> 8) << 6) + (((r >> 6) & 3) << 4) + (r & 15);
    const float* src = (k < 512) ? (Wx + (gate * 1024 + unit) * 512 + k)
                                 : (Wh + (gate * 1024 + unit) * 1024 + (k - 512));
    float4 v0 = *(const float4*)src;
    float4 v1 = *(const float4*)(src + 4);
    float f[8] = {v0.x, v0.y, v0.z, v0.w, v1.x, v1.y, v1.z, v1.w};
    unsigned short o[8];
#pragma unroll
    for (int i = 0; i < 8; ++i) o[i] = f2bf(f[i]);
    *(s16x8*)(Wg + base) = *(s16x8*)o;
  } else if (bid < 16384) {
    // Wz2: [1024][2048]: k<1024 -> W_lo(Whz), k>=1024 -> W_hi(Whz)
    const float* Whz = Wh + 3 * 1024 * 1024;
    int t = (bid - 15360) * 256 + threadIdx.x;
    int base = t * 8;
    int n = base >> 11;
    int k = base & 2047;
    int klo = (k < 1024) ? k : (k - 1024);
    const float* src = Whz + n * 1024 + klo;
    float4 v0 = *(const float4*)src;
    float4 v1 = *(const float4*)(src + 4);
    float f[8] = {v0.x, v0.y, v0.z, v0.w, v1.x, v1.y, v1.z, v1.w};
    unsigned short o[8];
    if (k < 1024) {
#pragma unroll
      for (int i = 0; i < 8; ++i) { unsigned short h_ = f2bf(f[i]); o[i] = f2bf(f[i] - bf2f(h_)); }
    } else {
#pragma unroll
      for (int i = 0; i < 8; ++i) o[i] = f2bf(f[i]);
    }
    *(s16x8*)(Wz2 + base) = *(s16x8*)o;
  } else {
    int t = (bid - 16384) * 256 + threadIdx.x;
    int base = t * 8;
    float4 v0 = *(const float4*)(Wout + base);
    float4 v1 = *(const float4*)(Wout + base + 4);
    float f[8] = {v0.x, v0.y, v0.z, v0.w, v1.x, v1.y, v1.z, v1.w};
    unsigned short o[8];
#pragma unroll
    for (int i = 0; i < 8; ++i) o[i] = f2bf(f[i]);
    *(s16x8*)(Wo + base) = *(s16x8*)o;
  }
}

// ===== 256x256 / 8-wave GEMM, flatmm structure: A via LDS, B global->regs =====
//
// Rationale (round-5 post-mortem): with A AND B in LDS, the CU LDS pipe carries
// ~3100 cyc/tile (192 b128 reads + 96 stage-writes) vs MFMA 2480 -> barrier-locked
// phases serialize the pipes at ~6400 cyc/tile. Moving B to per-lane global loads
// (AITER flatmm pattern) cuts LDS to ~1920 cyc/tile (< MFMA) and puts B on the
// vmem pipe, which needs no barriers and hides under MFMA via counted vmcnt.
//
// B fragment = B[n = n0+wn*64+ni*16+ln][k = kt*64 + ks*32 + qlane*8 .. +8] --
// identical to what the LDS path delivered (swizzle algebra: logical chunk
// j = qlane + 4*ks), so numerics are bit-identical. Each wave-load: 16 rows x
// 64B segments, L2-hot (per-XCD B-panels ~1.5 MB << 4 MB L2).
//
// LDS: lds[2][256*64 bf16] A double-buffer, 64 KiB. Chunk-rotation swizzle as
// before (0 conflicts). 1 block/CU (regs), 2 waves/SIMD.
//
// Tile t (phases = output quadrants, 1 barrier each; 5 barriers/tile):
//  ph0: AQ q0->aE; stage A(t+1)h0 -> dA[other]; BAR; vmcnt(2) [certs B(t),
//       leaves A(t+1)h0]; lgkm0; 16 MFMA q0
//  ph1: AQ q1->aO; stage A(t+1)h1;              BAR; lgkm0; 16 MFMA q1
//  ph2: AQ q2->aE;                              BAR; lgkm0; 16 MFMA q2
//  ph3: AQ q3->aO;                              BAR; lgkm0; 16 MFMA q3;
//       issue 8 B(t+1) global loads -> bq (after MFMA consumed old bq);
//       vmcnt(8) [certs A(t+1), leaves B(t+1)]; BAR
// Hazards: A(t+1)->dA[other] lands >=1 barrier + ~200cyc after every wave's
// dA[other] reads drained (t-1 ph3 lgkm0 precedes tile-end barrier). vmcnt waits
// never cover loads issued in the same phase. Last tile: vmcnt(0) at ph0 (only
// B(NT-1)'s 8 outstanding), no stages/loads.

#define VM8 asm volatile("s_waitcnt vmcnt(8)" ::: "memory")
#define VM2 asm volatile("s_waitcnt vmcnt(2)" ::: "memory")
#define VM0 asm volatile("s_waitcnt vmcnt(0)" ::: "memory")
#define LGKM0 asm volatile("s_waitcnt lgkmcnt(0)" ::: "memory")
#define SB0 __builtin_amdgcn_sched_barrier(0)
#define BARR __builtin_amdgcn_s_barrier()
#define VMNONE ((void)0)
#define NOST ((void)0)
#define NOBAR ((void)0)

#define RD_A(CA, MI, KS) (*(const s16x8*)((CA) + ((KS) ? aoff1 : aoff0) + (MI) * 1024))
// read one A quadrant (rows wm*128 + [2Q*16, 2Q*16+32)), both k-slices
#define AQ(S, CA, Q) do { \
  S[0] = RD_A(CA, 2 * (Q), 0);  S[1] = RD_A(CA, 2 * (Q) + 1, 0); \
  S[2] = RD_A(CA, 2 * (Q), 1);  S[3] = RD_A(CA, 2 * (Q) + 1, 1); } while (0)

// global B fragment load (forced global_load, not flat: AS(1) cast)
#define GBL(P) (*(const __attribute__((address_space(1))) s16x8*)(P))
#define BLOAD_CUR do { \
  bq[0] = GBL(gBv0);      bq[1] = GBL(gBv1);      bq[2] = GBL(gBv2);      bq[3] = GBL(gBv3); \
  bq[4] = GBL(gBv0 + 32); bq[5] = GBL(gBv1 + 32); bq[6] = GBL(gBv2 + 32); bq[7] = GBL(gBv3 + 32); \
} while (0)
#define BLOAD_NEXT do { \
  gBv0 += 64; gBv1 += 64; gBv2 += 64; gBv3 += 64; \
  BLOAD_CUR; \
} while (0)

// A half-tile stages (2 x stage16 each)
#define SA_H0(TT, DB) do { \
  stage16(gA[0][0] + (size_t)(TT) * 64, (DB)); \
  stage16(gA[0][1] + (size_t)(TT) * 64, (DB) + 4096); } while (0)
#define SA_H1(TT, DB) do { \
  stage16(gA[1][0] + (size_t)(TT) * 64, (DB) + 8192); \
  stage16(gA[1][1] + (size_t)(TT) * 64, (DB) + 12288); } while (0)
// zcorr A source switches at tile 16 (h_hi from Xb, then h_lo from Hlo)
#define ZSA_H0(TT, DB) do { \
  const unsigned short *z0_, *z1_; \
  if ((TT) < 16) { z0_ = gAX[0][0] + (size_t)(TT) * 64; z1_ = gAX[0][1] + (size_t)(TT) * 64; } \
  else { z0_ = gAH[0][0] + (size_t)((TT) - 16) * 64; z1_ = gAH[0][1] + (size_t)((TT) - 16) * 64; } \
  stage16(z0_, (DB)); stage16(z1_, (DB) + 4096); } while (0)
#define ZSA_H1(TT, DB) do { \
  const unsigned short *z2_, *z3_; \
  if ((TT) < 16) { z2_ = gAX[1][0] + (size_t)(TT) * 64; z3_ = gAX[1][1] + (size_t)(TT) * 64; } \
  else { z2_ = gAH[1][0] + (size_t)((TT) - 16) * 64; z3_ = gAH[1][1] + (size_t)((TT) - 16) * 64; } \
  stage16(z2_, (DB) + 8192); stage16(z3_, (DB) + 12288); } while (0)

// 16 MFMA for output quadrant Q (acc rows 2Q, 2Q+1)
#define MFMAQ(Q, S) do { \
  __builtin_amdgcn_s_setprio(1); \
  _Pragma("unroll") \
  for (int ni = 0; ni < 4; ++ni) { \
    acc[2 * (Q)    ][ni] = __builtin_amdgcn_mfma_f32_16x16x32_bf16(S[0], bq[ni], acc[2 * (Q)    ][ni], 0, 0, 0); \
    acc[2 * (Q) + 1][ni] = __builtin_amdgcn_mfma_f32_16x16x32_bf16(S[1], bq[ni], acc[2 * (Q) + 1][ni], 0, 0, 0); \
  } \
  _Pragma("unroll") \
  for (int ni = 0; ni < 4; ++ni) { \
    acc[2 * (Q)    ][ni] = __builtin_amdgcn_mfma_f32_16x16x32_bf16(S[2], bq[4 + ni], acc[2 * (Q)    ][ni], 0, 0, 0); \
    acc[2 * (Q) + 1][ni] = __builtin_amdgcn_mfma_f32_16x16x32_bf16(S[3], bq[4 + ni], acc[2 * (Q) + 1][ni], 0, 0, 0); \
  } \
  __builtin_amdgcn_s_setprio(0); \
} while (0)

#define KTILE(CA, S0, S1, VMB, BL3, VME, EBAR) do { \
  AQ(aE, CA, 0); S0; \
  BARR; VMB; LGKM0; SB0; \
  MFMAQ(0, aE); \
  AQ(aO, CA, 1); S1; \
  BARR; LGKM0; SB0; \
  MFMAQ(1, aO); \
  AQ(aE, CA, 2); \
  BARR; LGKM0; SB0; \
  MFMAQ(2, aE); \
  AQ(aO, CA, 3); \
  BARR; LGKM0; SB0; \
  MFMAQ(3, aO); \
  BL3; VME; EBAR; \
} while (0)

// Gate GEMM + fused LSTM epilogue. M=16384, N=4096 (permuted), K=1536, NT=24.
__global__ __launch_bounds__(512, 2) void gemm_gates2(const unsigned short* __restrict__ Xb,
                                                      const unsigned short* __restrict__ Wg,
                                                      const float* __restrict__ bx,
                                                      const float* __restrict__ cold,
                                                      const unsigned short* __restrict__ Dgz,
                                                      float* __restrict__ hnew,
                                                      unsigned short* __restrict__ hnewb) {
  __shared__ unsigned short lds[2][16384];   // 64 KiB, A only
  const int tid = threadIdx.x;
  const int lane = tid & 63, wave = tid >> 6;
  const int wm = wave & 1, wn = wave >> 1;
  const int ln = lane & 15, qlane = lane >> 4;
  // natural mapping: bx mod 8 pins each XCD to 2 B-panels (L2-resident)
  const int n0 = blockIdx.x << 8, m0 = blockIdx.y << 8;
  const int sr = tid >> 3;
  const int j = ((tid & 7) - (sr & 7)) & 7;

  const unsigned short* gA[2][2];
#pragma unroll
  for (int hh = 0; hh < 2; ++hh)
#pragma unroll
    for (int u = 0; u < 2; ++u) {
      const int row = hh * 128 + u * 64 + sr;
      gA[hh][u] = Xb + (size_t)(m0 + row) * 1536 + j * 8;
    }
  // B fragment base pointers: row = n0 + wn*64 + ni*16 + ln, col = qlane*8
  const unsigned short* gBv0 = Wg + (size_t)(n0 + wn * 64 +  0 + ln) * 1536 + qlane * 8;
  const unsigned short* gBv1 = Wg + (size_t)(n0 + wn * 64 + 16 + ln) * 1536 + qlane * 8;
  const unsigned short* gBv2 = Wg + (size_t)(n0 + wn * 64 + 32 + ln) * 1536 + qlane * 8;
  const unsigned short* gBv3 = Wg + (size_t)(n0 + wn * 64 + 48 + ln) * 1536 + qlane * 8;

  unsigned short* const dA0 = &lds[0][0] + (tid & ~63) * 8;
  unsigned short* const dA1 = &lds[1][0] + (tid & ~63) * 8;
  const unsigned short* const lA0 = &lds[0][0];
  const unsigned short* const lA1 = &lds[1][0];
  const int sl0 = ((qlane + ln) & 7) * 8;
  const int sl1 = sl0 ^ 32;
  const int aoff0 = (wm * 128 + ln) * 64 + sl0;
  const int aoff1 = (wm * 128 + ln) * 64 + sl1;

  f32x4 acc[8][4] = {};
  s16x8 bq[8], aE[4], aO[4];

  // prologue: stage A(0) (4 loads), issue B(0) (8 loads); vmcnt(8) certs A(0)
  SA_H0(0, dA0); SA_H1(0, dA0);
  BLOAD_CUR;
  VM8;
  BARR;

  KTILE(lA0, SA_H0(1, dA1), SA_H1(1, dA1), VM2, BLOAD_NEXT, VM8, BARR);  // t=0
#pragma unroll 1
  for (int t = 1; t < 21; t += 2) {
    KTILE(lA1, SA_H0(t + 1, dA0), SA_H1(t + 1, dA0), VM2, BLOAD_NEXT, VM8, BARR);
    KTILE(lA0, SA_H0(t + 2, dA1), SA_H1(t + 2, dA1), VM2, BLOAD_NEXT, VM8, BARR);
  }
  KTILE(lA1, SA_H0(22, dA0), SA_H1(22, dA0), VM2, BLOAD_NEXT, VM8, BARR);  // t=21
  KTILE(lA0, SA_H0(23, dA1), SA_H1(23, dA1), VM2, BLOAD_NEXT, VM8, BARR);  // t=22
  KTILE(lA1, NOST, NOST, VM0, NOST, VMNONE, NOBAR);                        // t=23

  // Epilogue: acc[mi][ni] is gate ni for unit = blkX*64 + wn*16 + ln.
  const int unit = ((int)blockIdx.x << 6) + (wn << 4) + ln;
  const float bi = bx[unit];
  const float bo = bx[1024 + unit];
  const float bfg = bx[2048 + unit];
  const float bz = bx[3072 + unit];
#pragma unroll
  for (int mi = 0; mi < 8; ++mi) {
#pragma unroll
    for (int r = 0; r < 4; ++r) {
      const int b = m0 + wm * 128 + mi * 16 + qlane * 4 + r;
      const int idx = b * 1024 + unit;
      const float gi = acc[mi][0][r] + bi;
      const float go = acc[mi][1][r] + bo;
      const float gf = acc[mi][2][r] + bfg;
      const float gz = acc[mi][3][r] + bz + bf2f(Dgz[idx]);
      const float iv = sigmoid_f(gi);
      const float ov = sigmoid_f(go);
      const float fv = sigmoid_f(gf);
      const float zv = tanh_f(gz);
      const float cn = iv * zv + fv * cold[idx];
      const float hn = ov * tanh_f(cn);
      hnew[idx] = hn;
      hnewb[idx] = f2bf(hn);
    }
  }
}

// Dgz[b,u] = sum_k h_hi*W_lo + h_lo*W_hi. M=16384, N=1024, K=2048, NT=32.
__global__ __launch_bounds__(512, 2) void gemm_zcorr2(const unsigned short* __restrict__ Xb,
                                                      const unsigned short* __restrict__ Hlo,
                                                      const unsigned short* __restrict__ Wz2,
                                                      unsigned short* __restrict__ Dgz) {
  __shared__ unsigned short lds[2][16384];
  const int tid = threadIdx.x;
  const int lane = tid & 63, wave = tid >> 6;
  const int wm = wave & 1, wn = wave >> 1;
  const int ln = lane & 15, qlane = lane >> 4;
  const int n0 = blockIdx.x << 8, m0 = blockIdx.y << 8;
  const int sr = tid >> 3;
  const int j = ((tid & 7) - (sr & 7)) & 7;

  const unsigned short* gAX[2][2];
  const unsigned short* gAH[2][2];
#pragma unroll
  for (int hh = 0; hh < 2; ++hh)
#pragma unroll
    for (int u = 0; u < 2; ++u) {
      const int row = hh * 128 + u * 64 + sr;
      gAX[hh][u] = Xb  + (size_t)(m0 + row) * 1536 + 512 + j * 8;
      gAH[hh][u] = Hlo + (size_t)(m0 + row) * 1024 + j * 8;
    }
  const unsigned short* gBv0 = Wz2 + (size_t)(n0 + wn * 64 +  0 + ln) * 2048 + qlane * 8;
  const unsigned short* gBv1 = Wz2 + (size_t)(n0 + wn * 64 + 16 + ln) * 2048 + qlane * 8;
  const unsigned short* gBv2 = Wz2 + (size_t)(n0 + wn * 64 + 32 + ln) * 2048 + qlane * 8;
  const unsigned short* gBv3 = Wz2 + (size_t)(n0 + wn * 64 + 48 + ln) * 2048 + qlane * 8;

  unsigned short* const dA0 = &lds[0][0] + (tid & ~63) * 8;
  unsigned short* const dA1 = &lds[1][0] + (tid & ~63) * 8;
  const unsigned short* const lA0 = &lds[0][0];
  const unsigned short* const lA1 = &lds[1][0];
  const int sl0 = ((qlane + ln) & 7) * 8;
  const int sl1 = sl0 ^ 32;
  const int aoff0 = (wm * 128 + ln) * 64 + sl0;
  const int aoff1 = (wm * 128 + ln) * 64 + sl1;

  f32x4 acc[8][4] = {};
  s16x8 bq[8], aE[4], aO[4];

  ZSA_H0(0, dA0); ZSA_H1(0, dA0);
  BLOAD_CUR;
  VM8;
  BARR;

  KTILE(lA0, ZSA_H0(1, dA1), ZSA_H1(1, dA1), VM2, BLOAD_NEXT, VM8, BARR);  // t=0
#pragma unroll 1
  for (int t = 1; t < 29; t += 2) {
    KTILE(lA1, ZSA_H0(t + 1, dA0), ZSA_H1(t + 1, dA0), VM2, BLOAD_NEXT, VM8, BARR);
    KTILE(lA0, ZSA_H0(t + 2, dA1), ZSA_H1(t + 2, dA1), VM2, BLOAD_NEXT, VM8, BARR);
  }
  KTILE(lA1, ZSA_H0(30, dA0), ZSA_H1(30, dA0), VM2, BLOAD_NEXT, VM8, BARR);  // t=29
  KTILE(lA0, ZSA_H0(31, dA1), ZSA_H1(31, dA1), VM2, BLOAD_NEXT, VM8, BARR);  // t=30
  KTILE(lA1, NOST, NOST, VM0, NOST, VMNONE, NOBAR);                          // t=31

#pragma unroll
  for (int mi = 0; mi < 8; ++mi) {
#pragma unroll
    for (int r = 0; r < 4; ++r) {
      const int b = m0 + wm * 128 + mi * 16 + qlane * 4 + r;
#pragma unroll
      for (int ni = 0; ni < 4; ++ni) {
        const int n = n0 + wn * 64 + ni * 16 + ln;
        Dgz[b * 1024 + n] = f2bf(acc[mi][ni][r]);
      }
    }
  }
}

// out = h_new @ Wout^T + bout. M=16384, N=512, K=1024.
__global__ __launch_bounds__(256) void gemm_out(const unsigned short* __restrict__ Hb,
                                                const unsigned short* __restrict__ Wo,
                                                const float* __restrict__ bout,
                                                float* __restrict__ out) {
  __shared__ unsigned short As[8192];
  __shared__ unsigned short Bs[8192];
  const int n0 = blockIdx.x * 128;
  const int m0 = blockIdx.y * 128;
  const int tid = threadIdx.x, lane = tid & 63, wave = tid >> 6;
  const unsigned short *ga[4], *gb[4];
  unsigned short *la[4], *lb[4];
#pragma unroll
  for (int u = 0; u < 4; ++u) {
    int p = u * 256 + tid;
    int r = p >> 3;
    int jj = ((p & 7) - r) & 7;
    ga[u] = Hb + (size_t)(m0 + r) * 1024 + jj * 8;
    gb[u] = Wo + (size_t)(n0 + r) * 1024 + jj * 8;
    la[u] = As + (u * 256 + (tid & ~63)) * 8;
    lb[u] = Bs + (u * 256 + (tid & ~63)) * 8;
  }
  f32x4 acc[4][4] = {};
  for (int kk = 0; kk < 16; ++kk) {
#pragma unroll
    for (int u = 0; u < 4; ++u) { stage16(ga[u], la[u]); stage16(gb[u], lb[u]); }
#pragma unroll
    for (int u = 0; u < 4; ++u) { ga[u] += 64; gb[u] += 64; }
    __syncthreads();
    mma_step64(As, Bs, acc, lane, wave);
    __syncthreads();
  }
  const int wm = wave & 1, wn = wave >> 1;
  const int ln = lane & 15, q = lane >> 4;
  float bo_[4];
#pragma unroll
  for (int ni = 0; ni < 4; ++ni) bo_[ni] = bout[n0 + wn * 64 + ni * 16 + ln];
#pragma unroll
  for (int mi = 0; mi < 4; ++mi) {
#pragma unroll
    for (int r = 0; r < 4; ++r) {
      const int b = m0 + wm * 64 + mi * 16 + q * 4 + r;
#pragma unroll
      for (int ni = 0; ni < 4; ++ni) {
        const int n = n0 + wn * 64 + ni * 16 + ln;
        out[b * 512 + n] = acc[mi][ni][r] + bo_[ni];
      }
    }
  }
}

extern "C" void kernel_launch(void* const* d_in, const int* in_sizes, int n_in,
                              void* d_out, int out_size, void* d_ws, size_t ws_size,
                              hipStream_t stream) {
  const float* inp  = (const float*)d_in[0];
  const float* h    = (const float*)d_in[1];
  const float* c    = (const float*)d_in[2];
  const float* Wx   = (const float*)d_in[3];
  const float* bx   = (const float*)d_in[4];
  const float* Wh   = (const float*)d_in[5];
  const float* Wout = (const float*)d_in[6];
  const float* bout = (const float*)d_in[7];

  float* out  = (float*)d_out;                       // [B, 512]
  float* hnew = out + (size_t)BB * OO;               // [B, 1024]

  char* ws = (char*)d_ws;
  unsigned short* Xb  = (unsigned short*)(ws);                  //  50,331,648 B
  unsigned short* Wg  = (unsigned short*)(ws + 50331648);       //  12,582,912 B
  unsigned short* Wo  = (unsigned short*)(ws + 62914560);       //   1,048,576 B
  unsigned short* Hb  = (unsigned short*)(ws + 63963136);       //  33,554,432 B
  unsigned short* Hlo = (unsigned short*)(ws + 97517568);       //  33,554,432 B
  unsigned short* Wz2 = (unsigned short*)(ws + 131072000);      //   4,194,304 B
  unsigned short* Dgz = (unsigned short*)(ws + 135266304);      //  33,554,432 B

  prep_all<<<16640, 256, 0, stream>>>(inp, h, Wx, Wh, Wout, Xb, Hlo, Wg, Wz2, Wo);
  gemm_zcorr2<<<dim3(4, 64),  512, 0, stream>>>(Xb, Hlo, Wz2, Dgz);
  gemm_gates2<<<dim3(16, 64), 512, 0, stream>>>(Xb, Wg, bx, c, Dgz, hnew, Hb);
  gemm_out  <<<dim3(4, 128),  256, 0, stream>>>(Hb, Wo, bout, out);
}